// Round 7
// baseline (550.440 us; speedup 1.0000x reference)
//
#include <hip/hip_runtime.h>

// ---------------------------------------------------------------------------
// CustomGCN: 2 dense layers + 3 GCNConv layers + per-layer (max||mean) pool.
// R1: binary-search cntG (removed 634us atomic wall).
// R2: bf16 hidden pipeline; MFMA bf16 GEMMs; bf16 gather table.
// R3: k_agg 8-deep gather pipeline.
// R4: CSC build with ONE u64 atomic/edge (count<<52 | w*2^32), atomic-free fill.
// R5: CSC record interleaved (8B); dinv folded into scan1.
// R6: rec packed to 4B ((bf16(w)<<17)|src, valid for N<2^17, w>=0); eslot u8;
//     agg pipeline 16-deep. Halves phase2 write-allocate + agg edge stream.
// ---------------------------------------------------------------------------

typedef __attribute__((ext_vector_type(8))) short bf16x8;
typedef __attribute__((ext_vector_type(4))) float f32x4;
typedef unsigned long long u64;
typedef unsigned int u32;

#define FRACBITS 52
#define FRACMASK ((1ULL << FRACBITS) - 1ULL)

__device__ __forceinline__ unsigned short f2b(float f) {  // RNE f32->bf16
    unsigned int u = __float_as_uint(f);
    return (unsigned short)((u + 0x7fffu + ((u >> 16) & 1u)) >> 16);
}
__device__ __forceinline__ float b2f(unsigned short h) {
    return __uint_as_float((unsigned int)h << 16);
}

// ---------------- preprocessing --------------------------------------------
__global__ __launch_bounds__(256) void k_init(u64* __restrict__ pk,
                                              float* __restrict__ gmax, float* __restrict__ gsum,
                                              int n, int npool)
{
    int i = blockIdx.x * 256 + threadIdx.x;
    if (i < n) pk[i] = 0ULL;
    if (i < npool) { gmax[i] = 0.0f; gsum[i] = 0.0f; }
}

// one u64 atomic per edge: count in [52:63], weight-sum fixed-point in [0:51]
__global__ __launch_bounds__(256) void k_phase1(const int* __restrict__ ei,
                                                const float* __restrict__ ew,
                                                u64* pk,
                                                unsigned char* __restrict__ eslot, int e)
{
    int i = blockIdx.x * 256 + threadIdx.x;
    if (i >= e) return;
    int c = ei[e + i];
    float w = ew[i];
    u64 fixed = (u64)((double)w * 4294967296.0);
    u64 packed = (1ULL << FRACBITS) | fixed;
    u64 old = atomicAdd(&pk[c], packed);
    eslot[i] = (unsigned char)(old >> FRACBITS);   // max degree << 256
}

__global__ void k_gcnt(const int* __restrict__ batch, float* __restrict__ cntG, int n, int g)
{
    int t = threadIdx.x;
    if (t >= g) return;
    int lo0 = 0, hi0 = n;
    while (lo0 < hi0) { int m = (lo0 + hi0) >> 1; if (batch[m] < t) lo0 = m + 1; else hi0 = m; }
    int lo1 = lo0, hi1 = n, t1 = t + 1;
    while (lo1 < hi1) { int m = (lo1 + hi1) >> 1; if (batch[m] < t1) lo1 = m + 1; else hi1 = m; }
    cntG[t] = (float)(lo1 - lo0);
}

// ---- exclusive scan of counts (pk>>52) into start[0..n); also emits dinv ---
__global__ __launch_bounds__(256) void k_scan1(const u64* __restrict__ pk,
                                               int* __restrict__ start,
                                               float* __restrict__ dinv,
                                               int* __restrict__ partials, int n)
{
    __shared__ int s[256];
    int t = threadIdx.x;
    int base = blockIdx.x * 1024 + t * 4;
    int v[4];
#pragma unroll
    for (int j = 0; j < 4; ++j) {
        int idx = base + j;
        if (idx < n) {
            u64 q = pk[idx];
            v[j] = (int)(q >> FRACBITS);
            float deg = 1.0f + (float)((double)(q & FRACMASK) * (1.0 / 4294967296.0));
            dinv[idx] = 1.0f / sqrtf(deg);
        } else v[j] = 0;
    }
    int tsum = v[0] + v[1] + v[2] + v[3];
    s[t] = tsum; __syncthreads();
    for (int off = 1; off < 256; off <<= 1) {
        int xv = (t >= off) ? s[t - off] : 0;
        __syncthreads();
        s[t] += xv;
        __syncthreads();
    }
    if (t == 255) partials[blockIdx.x] = s[255];
    int run = s[t] - tsum;
#pragma unroll
    for (int j = 0; j < 4; ++j) { int idx = base + j; if (idx < n) start[idx] = run; run += v[j]; }
}

__global__ __launch_bounds__(256) void k_scan2(int* partials, int nb)
{
    __shared__ int s[256];
    int t = threadIdx.x;
    int offset = 0;
    for (int b0 = 0; b0 < nb; b0 += 256) {
        int v = (b0 + t < nb) ? partials[b0 + t] : 0;
        s[t] = v; __syncthreads();
        for (int off = 1; off < 256; off <<= 1) {
            int xv = (t >= off) ? s[t - off] : 0;
            __syncthreads();
            s[t] += xv;
            __syncthreads();
        }
        int excl = s[t] - v;
        int tot = s[255];
        if (b0 + t < nb) partials[b0 + t] = offset + excl;
        offset += tot;
        __syncthreads();
    }
}

__global__ __launch_bounds__(256) void k_scan3(int* __restrict__ start,
                                               const int* __restrict__ partials, int n, int total)
{
    int i = blockIdx.x * 256 + threadIdx.x;
    if (i < n) start[i] += partials[i >> 10];
    if (i == 0) start[n] = total;
}

// ---- atomic-free fill: one 4B record ((bf16w)<<17 | src) per edge ----------
__global__ __launch_bounds__(256) void k_phase2(const int* __restrict__ ei, const float* __restrict__ ew,
                                                const float* __restrict__ dinv,
                                                const int* __restrict__ start,
                                                const unsigned char* __restrict__ eslot,
                                                u32* __restrict__ rec, int e)
{
    int i = blockIdx.x * 256 + threadIdx.x;
    if (i >= e) return;
    int r = ei[i], c = ei[e + i];
    int idx = start[c] + eslot[i];
    float w = dinv[r] * ew[i] * dinv[c];           // w >= 0
    u32 wb = f2b(w);                                // sign bit 0 -> 15 useful bits
    rec[idx] = (wb << 17) | (u32)r;                 // requires N < 2^17
}

// ---------------- weight linearization into MFMA fragment order ------------
__global__ __launch_bounds__(256) void k_wfrag(const float* __restrict__ W, unsigned short* __restrict__ Wf)
{
    int idx = blockIdx.x * 256 + threadIdx.x;   // [0, 2048)
    if (idx >= 2048) return;
    int ctkt = idx >> 6, lane = idx & 63;
    int kt = ctkt & 3, ct = ctkt >> 2;
    int k0 = kt * 32 + (lane >> 4) * 8;
    int col = ct * 16 + (lane & 15);
    bf16x8 v;
#pragma unroll
    for (int j = 0; j < 8; ++j) v[j] = (short)f2b(W[(k0 + j) * 128 + col]);
    *(bf16x8*)&Wf[(size_t)idx * 8] = v;
}

// ---------------- MFMA GEMM: C[M,128] = A[M,128] @ W[128,128] --------------
__global__ __launch_bounds__(256) void k_gemm_mf(const unsigned short* __restrict__ A,
                                                 const float* __restrict__ Af32,
                                                 const unsigned short* __restrict__ Wf,
                                                 const float* __restrict__ bias,
                                                 unsigned short* __restrict__ C,
                                                 int relu, int M)
{
    int t = threadIdx.x;
    int lane = t & 63, w = t >> 6;
    int s = blockIdx.x * 4 + w;
    if (s * 16 >= M) return;
    int r0 = s * 16;
    int row = r0 + (lane & 15);
    int k0 = (lane >> 4) * 8;

    bf16x8 af[4];
    if (A) {
#pragma unroll
        for (int kt = 0; kt < 4; ++kt) {
            bf16x8 a = {0,0,0,0,0,0,0,0};
            if (row < M) a = *(const bf16x8*)&A[(size_t)row * 128 + k0 + kt * 32];
            af[kt] = a;
        }
    } else {
#pragma unroll
        for (int kt = 0; kt < 4; ++kt) {
            bf16x8 a = {0,0,0,0,0,0,0,0};
            if (row < M) {
                const float4* A4 = (const float4*)(Af32 + (size_t)row * 128 + k0 + kt * 32);
                float4 p = A4[0], q = A4[1];
                a[0] = (short)f2b(p.x); a[1] = (short)f2b(p.y);
                a[2] = (short)f2b(p.z); a[3] = (short)f2b(p.w);
                a[4] = (short)f2b(q.x); a[5] = (short)f2b(q.y);
                a[6] = (short)f2b(q.z); a[7] = (short)f2b(q.w);
            }
            af[kt] = a;
        }
    }

    int orow = r0 + 4 * (lane >> 4);
    int ocol = lane & 15;
#pragma unroll
    for (int ct = 0; ct < 8; ++ct) {
        f32x4 acc = {0.f, 0.f, 0.f, 0.f};
#pragma unroll
        for (int kt = 0; kt < 4; ++kt) {
            bf16x8 b = *(const bf16x8*)&Wf[(size_t)(((ct << 2) | kt) * 64 + lane) * 8];
            acc = __builtin_amdgcn_mfma_f32_16x16x32_bf16(af[kt], b, acc, 0, 0, 0);
        }
        float bv = bias ? bias[ct * 16 + ocol] : 0.f;
#pragma unroll
        for (int j = 0; j < 4; ++j) {
            int rr = orow + j;
            if (rr < M) {
                float v = acc[j] + bv;
                if (relu) v = fmaxf(v, 0.f);
                C[(size_t)rr * 128 + ct * 16 + ocol] = f2b(v);
            }
        }
    }
}

// ---------------- pull aggregation: 16-deep gather pipeline ----------------
__global__ __launch_bounds__(256) void k_agg(const u32* __restrict__ xw,
                                             const int* __restrict__ start,
                                             const u32* __restrict__ rec,
                                             const float* __restrict__ dinv, const float* __restrict__ bias,
                                             u32* __restrict__ hout, int n)
{
    int wid  = (blockIdx.x * 256 + threadIdx.x) >> 6;
    int lane = threadIdx.x & 63;
    if (wid >= n) return;
    float di = dinv[wid];
    float sn = di * di;
    u32 v = xw[(size_t)wid * 64 + lane];
    float ax = __uint_as_float(v << 16) * sn;
    float ay = __uint_as_float(v & 0xffff0000u) * sn;
    int s0 = start[wid], s1 = start[wid + 1];

    int j = s0;
    for (; j + 16 <= s1; j += 16) {
        u32 rc[16];
#pragma unroll
        for (int q = 0; q < 16; ++q) rc[q] = rec[j + q];
        u32 u[16];
#pragma unroll
        for (int q = 0; q < 16; ++q) u[q] = xw[(size_t)(rc[q] & 0x1FFFFu) * 64 + lane];
#pragma unroll
        for (int q = 0; q < 16; ++q) {
            float w = __uint_as_float((rc[q] >> 17) << 16);
            ax = fmaf(w, __uint_as_float(u[q] << 16), ax);
            ay = fmaf(w, __uint_as_float(u[q] & 0xffff0000u), ay);
        }
    }
    {
        int rem = s1 - j;
        u32 rc[16];
#pragma unroll
        for (int q = 0; q < 16; ++q) rc[q] = (q < rem) ? rec[j + q] : 0u;
        u32 u[16];
#pragma unroll
        for (int q = 0; q < 16; ++q) u[q] = (q < rem) ? xw[(size_t)(rc[q] & 0x1FFFFu) * 64 + lane] : 0u;
#pragma unroll
        for (int q = 0; q < 16; ++q) {
            float w = __uint_as_float((rc[q] >> 17) << 16);
            ax = fmaf(w, __uint_as_float(u[q] << 16), ax);
            ay = fmaf(w, __uint_as_float(u[q] & 0xffff0000u), ay);
        }
    }

    ax = fmaxf(ax + bias[lane * 2], 0.f);
    ay = fmaxf(ay + bias[lane * 2 + 1], 0.f);
    hout[(size_t)wid * 64 + lane] = (u32)f2b(ax) | ((u32)f2b(ay) << 16);
}

// ---------------- pooling (bf16 in) ----------------------------------------
__global__ __launch_bounds__(256) void k_pool(const unsigned short* __restrict__ h,
                                              const int* __restrict__ batch,
                                              float* gmax, float* gsum, int n)
{
    int c = threadIdx.x & 127, sub = threadIdx.x >> 7;
    int r0 = blockIdx.x * 128;
    int rend = min(r0 + 128, n);
    float mx = 0.f, sm = 0.f;
    int cur = -1;
    for (int r = r0 + sub; r < rend; r += 2) {
        int b = batch[r];
        if (b != cur) {
            if (cur >= 0) {
                atomicMax((unsigned int*)&gmax[cur * 128 + c], __float_as_uint(mx));
                atomicAdd(&gsum[cur * 128 + c], sm);
            }
            cur = b; mx = 0.f; sm = 0.f;
        }
        float v = b2f(h[(size_t)r * 128 + c]);
        mx = fmaxf(mx, v);
        sm += v;
    }
    if (cur >= 0) {
        atomicMax((unsigned int*)&gmax[cur * 128 + c], __float_as_uint(mx));
        atomicAdd(&gsum[cur * 128 + c], sm);
    }
}

__global__ __launch_bounds__(256) void k_final(const float* __restrict__ gmax, const float* __restrict__ gsum,
                                               const float* __restrict__ cntG, float* __restrict__ out,
                                               int G, int L)
{
    int i = blockIdx.x * 256 + threadIdx.x;
    int tot = L * G * 128;
    if (i >= tot) return;
    int c = i & 127;
    int g = (i >> 7) % G;
    int l = i / (G * 128);
    float ct = fmaxf(cntG[g], 1.0f);
    out[(size_t)g * (L * 256) + l * 256 + c]       = gmax[i];
    out[(size_t)g * (L * 256) + l * 256 + 128 + c] = gsum[i] / ct;
}

static inline int divup(int a, int b) { return (a + b - 1) / b; }

extern "C" void kernel_launch(void* const* d_in, const int* in_sizes, int n_in,
                              void* d_out, int out_size, void* d_ws, size_t ws_size,
                              hipStream_t stream)
{
    const float* x     = (const float*)d_in[0];
    const float* ew    = (const float*)d_in[1];
    const float* W1    = (const float*)d_in[2];
    const float* b1    = (const float*)d_in[3];
    const float* W2    = (const float*)d_in[4];
    const float* b2    = (const float*)d_in[5];
    const float* cW    = (const float*)d_in[6];
    const float* cB    = (const float*)d_in[7];
    const int*   ei    = (const int*)d_in[8];
    const int*   batch = (const int*)d_in[9];
    float* out = (float*)d_out;

    const int E = in_sizes[1];
    const int N = in_sizes[9];
    const int L = in_sizes[7] / 128;
    const int G = out_size / (L * 256);

    char* p = (char*)d_ws;
    auto carve = [&](size_t bytes) -> void* {
        void* q = (void*)p;
        p += (bytes + 255) & ~(size_t)255;
        return q;
    };
    u64*   pk       = (u64*)  carve((size_t)N * 8);
    float* dinv     = (float*)carve((size_t)N * 4);
    int*   start    = (int*)  carve((size_t)(N + 1) * 4);
    unsigned char* eslot = (unsigned char*)carve((size_t)E);
    int*   partials = (int*)  carve(4096);
    u32*   rec      = (u32*)  carve((size_t)E * 4);
    float* gmax     = (float*)carve((size_t)L * G * 128 * 4);
    float* gsum     = (float*)carve((size_t)L * G * 128 * 4);
    float* cntG     = (float*)carve((size_t)G * 4);
    unsigned short* wf[5];
    for (int i = 0; i < 5; ++i) wf[i] = (unsigned short*)carve(16384 * 2);
    unsigned short* xwb = (unsigned short*)carve((size_t)N * 128 * 2);
    unsigned short* hbA = (unsigned short*)carve((size_t)N * 128 * 2);
    unsigned short* hbB = (unsigned short*)carve((size_t)N * 128 * 2);

    const int npool = L * G * 128;

    // --- preprocessing -----------------------------------------------------
    {
        int mx = N > npool ? N : npool;
        k_init<<<divup(mx, 256), 256, 0, stream>>>(pk, gmax, gsum, N, npool);
    }
    k_phase1<<<divup(E, 256), 256, 0, stream>>>(ei, ew, pk, eslot, E);
    k_gcnt<<<1, 64, 0, stream>>>(batch, cntG, N, G);

    int nb1 = divup(N, 1024);
    k_scan1<<<nb1, 256, 0, stream>>>(pk, start, dinv, partials, N);
    k_scan2<<<1, 256, 0, stream>>>(partials, nb1);
    k_scan3<<<divup(N, 256), 256, 0, stream>>>(start, partials, N, E);
    k_phase2<<<divup(E, 256), 256, 0, stream>>>(ei, ew, dinv, start, eslot, rec, E);

    // --- weight fragment linearization ------------------------------------
    k_wfrag<<<8, 256, 0, stream>>>(W1, wf[0]);
    k_wfrag<<<8, 256, 0, stream>>>(W2, wf[1]);
    for (int l = 0; l < L && l < 3; ++l)
        k_wfrag<<<8, 256, 0, stream>>>(cW + (size_t)l * 16384, wf[2 + l]);

    // --- dense encoder -----------------------------------------------------
    int gblocks = divup(N, 64);
    k_gemm_mf<<<gblocks, 256, 0, stream>>>(nullptr, x, wf[0], b1, hbA, 1, N);
    k_gemm_mf<<<gblocks, 256, 0, stream>>>(hbA, nullptr, wf[1], b2, hbB, 1, N);

    // --- conv layers + pooling --------------------------------------------
    int ablocks = divup(N, 4);
    int pblocks = divup(N, 128);
    unsigned short* cur = hbB;
    unsigned short* alt = hbA;
    for (int l = 0; l < L; ++l) {
        k_gemm_mf<<<gblocks, 256, 0, stream>>>(cur, nullptr, wf[2 + (l < 3 ? l : 2)], nullptr, xwb, 0, N);
        k_agg<<<ablocks, 256, 0, stream>>>((const u32*)xwb, start, rec, dinv,
                                           cB + (size_t)l * 128, (u32*)alt, N);
        k_pool<<<pblocks, 256, 0, stream>>>(alt, batch, gmax + (size_t)l * G * 128,
                                            gsum + (size_t)l * G * 128, N);
        unsigned short* tmp = cur; cur = alt; alt = tmp;
    }

    k_final<<<divup(L * G * 128, 256), 256, 0, stream>>>(gmax, gsum, cntG, out, G, L);
}

// Round 8
// 524.371 us; speedup vs baseline: 1.0497x; 1.0497x over previous
//
#include <hip/hip_runtime.h>

// ---------------------------------------------------------------------------
// CustomGCN: 2 dense layers + 3 GCNConv layers + per-layer (max||mean) pool.
// R1: binary-search cntG (removed 634us atomic wall).
// R2: bf16 hidden pipeline; MFMA bf16 GEMMs; bf16 gather table.
// R3: k_agg 8-deep gather pipeline.
// R4: CSC build with ONE u64 atomic/edge (count<<52 | w*2^32), atomic-free fill.
// R5: CSC record interleaved (8B); dinv folded into scan1.
// R6: rec packed to 4B ((bf16(w)<<17)|src); eslot u8. [16-deep agg REGRESSED]
// R7: agg back to 8-deep (16-deep wasted ~50% tail slots at mean degree 16
//     and over-queued gathers: 65->77us, VALUBusy 20->57%). Keep 4B rec.
// ---------------------------------------------------------------------------

typedef __attribute__((ext_vector_type(8))) short bf16x8;
typedef __attribute__((ext_vector_type(4))) float f32x4;
typedef unsigned long long u64;
typedef unsigned int u32;

#define FRACBITS 52
#define FRACMASK ((1ULL << FRACBITS) - 1ULL)

__device__ __forceinline__ unsigned short f2b(float f) {  // RNE f32->bf16
    unsigned int u = __float_as_uint(f);
    return (unsigned short)((u + 0x7fffu + ((u >> 16) & 1u)) >> 16);
}
__device__ __forceinline__ float b2f(unsigned short h) {
    return __uint_as_float((unsigned int)h << 16);
}

// ---------------- preprocessing --------------------------------------------
__global__ __launch_bounds__(256) void k_init(u64* __restrict__ pk,
                                              float* __restrict__ gmax, float* __restrict__ gsum,
                                              int n, int npool)
{
    int i = blockIdx.x * 256 + threadIdx.x;
    if (i < n) pk[i] = 0ULL;
    if (i < npool) { gmax[i] = 0.0f; gsum[i] = 0.0f; }
}

// one u64 atomic per edge: count in [52:63], weight-sum fixed-point in [0:51]
__global__ __launch_bounds__(256) void k_phase1(const int* __restrict__ ei,
                                                const float* __restrict__ ew,
                                                u64* pk,
                                                unsigned char* __restrict__ eslot, int e)
{
    int i = blockIdx.x * 256 + threadIdx.x;
    if (i >= e) return;
    int c = ei[e + i];
    float w = ew[i];
    u64 fixed = (u64)((double)w * 4294967296.0);
    u64 packed = (1ULL << FRACBITS) | fixed;
    u64 old = atomicAdd(&pk[c], packed);
    eslot[i] = (unsigned char)(old >> FRACBITS);   // max degree << 256
}

__global__ void k_gcnt(const int* __restrict__ batch, float* __restrict__ cntG, int n, int g)
{
    int t = threadIdx.x;
    if (t >= g) return;
    int lo0 = 0, hi0 = n;
    while (lo0 < hi0) { int m = (lo0 + hi0) >> 1; if (batch[m] < t) lo0 = m + 1; else hi0 = m; }
    int lo1 = lo0, hi1 = n, t1 = t + 1;
    while (lo1 < hi1) { int m = (lo1 + hi1) >> 1; if (batch[m] < t1) lo1 = m + 1; else hi1 = m; }
    cntG[t] = (float)(lo1 - lo0);
}

// ---- exclusive scan of counts (pk>>52) into start[0..n); also emits dinv ---
__global__ __launch_bounds__(256) void k_scan1(const u64* __restrict__ pk,
                                               int* __restrict__ start,
                                               float* __restrict__ dinv,
                                               int* __restrict__ partials, int n)
{
    __shared__ int s[256];
    int t = threadIdx.x;
    int base = blockIdx.x * 1024 + t * 4;
    int v[4];
#pragma unroll
    for (int j = 0; j < 4; ++j) {
        int idx = base + j;
        if (idx < n) {
            u64 q = pk[idx];
            v[j] = (int)(q >> FRACBITS);
            float deg = 1.0f + (float)((double)(q & FRACMASK) * (1.0 / 4294967296.0));
            dinv[idx] = 1.0f / sqrtf(deg);
        } else v[j] = 0;
    }
    int tsum = v[0] + v[1] + v[2] + v[3];
    s[t] = tsum; __syncthreads();
    for (int off = 1; off < 256; off <<= 1) {
        int xv = (t >= off) ? s[t - off] : 0;
        __syncthreads();
        s[t] += xv;
        __syncthreads();
    }
    if (t == 255) partials[blockIdx.x] = s[255];
    int run = s[t] - tsum;
#pragma unroll
    for (int j = 0; j < 4; ++j) { int idx = base + j; if (idx < n) start[idx] = run; run += v[j]; }
}

__global__ __launch_bounds__(256) void k_scan2(int* partials, int nb)
{
    __shared__ int s[256];
    int t = threadIdx.x;
    int offset = 0;
    for (int b0 = 0; b0 < nb; b0 += 256) {
        int v = (b0 + t < nb) ? partials[b0 + t] : 0;
        s[t] = v; __syncthreads();
        for (int off = 1; off < 256; off <<= 1) {
            int xv = (t >= off) ? s[t - off] : 0;
            __syncthreads();
            s[t] += xv;
            __syncthreads();
        }
        int excl = s[t] - v;
        int tot = s[255];
        if (b0 + t < nb) partials[b0 + t] = offset + excl;
        offset += tot;
        __syncthreads();
    }
}

__global__ __launch_bounds__(256) void k_scan3(int* __restrict__ start,
                                               const int* __restrict__ partials, int n, int total)
{
    int i = blockIdx.x * 256 + threadIdx.x;
    if (i < n) start[i] += partials[i >> 10];
    if (i == 0) start[n] = total;
}

// ---- atomic-free fill: one 4B record ((bf16w)<<17 | src) per edge ----------
__global__ __launch_bounds__(256) void k_phase2(const int* __restrict__ ei, const float* __restrict__ ew,
                                                const float* __restrict__ dinv,
                                                const int* __restrict__ start,
                                                const unsigned char* __restrict__ eslot,
                                                u32* __restrict__ rec, int e)
{
    int i = blockIdx.x * 256 + threadIdx.x;
    if (i >= e) return;
    int r = ei[i], c = ei[e + i];
    int idx = start[c] + eslot[i];
    float w = dinv[r] * ew[i] * dinv[c];           // w >= 0
    u32 wb = f2b(w);                                // sign bit 0 -> 15 useful bits
    rec[idx] = (wb << 17) | (u32)r;                 // requires N < 2^17
}

// ---------------- weight linearization into MFMA fragment order ------------
__global__ __launch_bounds__(256) void k_wfrag(const float* __restrict__ W, unsigned short* __restrict__ Wf)
{
    int idx = blockIdx.x * 256 + threadIdx.x;   // [0, 2048)
    if (idx >= 2048) return;
    int ctkt = idx >> 6, lane = idx & 63;
    int kt = ctkt & 3, ct = ctkt >> 2;
    int k0 = kt * 32 + (lane >> 4) * 8;
    int col = ct * 16 + (lane & 15);
    bf16x8 v;
#pragma unroll
    for (int j = 0; j < 8; ++j) v[j] = (short)f2b(W[(k0 + j) * 128 + col]);
    *(bf16x8*)&Wf[(size_t)idx * 8] = v;
}

// ---------------- MFMA GEMM: C[M,128] = A[M,128] @ W[128,128] --------------
__global__ __launch_bounds__(256) void k_gemm_mf(const unsigned short* __restrict__ A,
                                                 const float* __restrict__ Af32,
                                                 const unsigned short* __restrict__ Wf,
                                                 const float* __restrict__ bias,
                                                 unsigned short* __restrict__ C,
                                                 int relu, int M)
{
    int t = threadIdx.x;
    int lane = t & 63, w = t >> 6;
    int s = blockIdx.x * 4 + w;
    if (s * 16 >= M) return;
    int r0 = s * 16;
    int row = r0 + (lane & 15);
    int k0 = (lane >> 4) * 8;

    bf16x8 af[4];
    if (A) {
#pragma unroll
        for (int kt = 0; kt < 4; ++kt) {
            bf16x8 a = {0,0,0,0,0,0,0,0};
            if (row < M) a = *(const bf16x8*)&A[(size_t)row * 128 + k0 + kt * 32];
            af[kt] = a;
        }
    } else {
#pragma unroll
        for (int kt = 0; kt < 4; ++kt) {
            bf16x8 a = {0,0,0,0,0,0,0,0};
            if (row < M) {
                const float4* A4 = (const float4*)(Af32 + (size_t)row * 128 + k0 + kt * 32);
                float4 p = A4[0], q = A4[1];
                a[0] = (short)f2b(p.x); a[1] = (short)f2b(p.y);
                a[2] = (short)f2b(p.z); a[3] = (short)f2b(p.w);
                a[4] = (short)f2b(q.x); a[5] = (short)f2b(q.y);
                a[6] = (short)f2b(q.z); a[7] = (short)f2b(q.w);
            }
            af[kt] = a;
        }
    }

    int orow = r0 + 4 * (lane >> 4);
    int ocol = lane & 15;
#pragma unroll
    for (int ct = 0; ct < 8; ++ct) {
        f32x4 acc = {0.f, 0.f, 0.f, 0.f};
#pragma unroll
        for (int kt = 0; kt < 4; ++kt) {
            bf16x8 b = *(const bf16x8*)&Wf[(size_t)(((ct << 2) | kt) * 64 + lane) * 8];
            acc = __builtin_amdgcn_mfma_f32_16x16x32_bf16(af[kt], b, acc, 0, 0, 0);
        }
        float bv = bias ? bias[ct * 16 + ocol] : 0.f;
#pragma unroll
        for (int j = 0; j < 4; ++j) {
            int rr = orow + j;
            if (rr < M) {
                float v = acc[j] + bv;
                if (relu) v = fmaxf(v, 0.f);
                C[(size_t)rr * 128 + ct * 16 + ocol] = f2b(v);
            }
        }
    }
}

// ---------------- pull aggregation: 8-deep gather pipeline -----------------
__global__ __launch_bounds__(256) void k_agg(const u32* __restrict__ xw,
                                             const int* __restrict__ start,
                                             const u32* __restrict__ rec,
                                             const float* __restrict__ dinv, const float* __restrict__ bias,
                                             u32* __restrict__ hout, int n)
{
    int wid  = (blockIdx.x * 256 + threadIdx.x) >> 6;
    int lane = threadIdx.x & 63;
    if (wid >= n) return;
    float di = dinv[wid];
    float sn = di * di;
    u32 v = xw[(size_t)wid * 64 + lane];
    float ax = __uint_as_float(v << 16) * sn;
    float ay = __uint_as_float(v & 0xffff0000u) * sn;
    int s0 = start[wid], s1 = start[wid + 1];

    int j = s0;
    for (; j + 8 <= s1; j += 8) {
        u32 rc[8];
#pragma unroll
        for (int q = 0; q < 8; ++q) rc[q] = rec[j + q];
        u32 u[8];
#pragma unroll
        for (int q = 0; q < 8; ++q) u[q] = xw[(size_t)(rc[q] & 0x1FFFFu) * 64 + lane];
#pragma unroll
        for (int q = 0; q < 8; ++q) {
            float w = __uint_as_float((rc[q] >> 17) << 16);
            ax = fmaf(w, __uint_as_float(u[q] << 16), ax);
            ay = fmaf(w, __uint_as_float(u[q] & 0xffff0000u), ay);
        }
    }
    int rem = s1 - j;
    if (rem) {
        u32 rc[8];
#pragma unroll
        for (int q = 0; q < 8; ++q) rc[q] = (q < rem) ? rec[j + q] : 0u;
        u32 u[8];
#pragma unroll
        for (int q = 0; q < 8; ++q) u[q] = (q < rem) ? xw[(size_t)(rc[q] & 0x1FFFFu) * 64 + lane] : 0u;
#pragma unroll
        for (int q = 0; q < 8; ++q) {
            float w = __uint_as_float((rc[q] >> 17) << 16);
            ax = fmaf(w, __uint_as_float(u[q] << 16), ax);
            ay = fmaf(w, __uint_as_float(u[q] & 0xffff0000u), ay);
        }
    }

    ax = fmaxf(ax + bias[lane * 2], 0.f);
    ay = fmaxf(ay + bias[lane * 2 + 1], 0.f);
    hout[(size_t)wid * 64 + lane] = (u32)f2b(ax) | ((u32)f2b(ay) << 16);
}

// ---------------- pooling (bf16 in) ----------------------------------------
__global__ __launch_bounds__(256) void k_pool(const unsigned short* __restrict__ h,
                                              const int* __restrict__ batch,
                                              float* gmax, float* gsum, int n)
{
    int c = threadIdx.x & 127, sub = threadIdx.x >> 7;
    int r0 = blockIdx.x * 128;
    int rend = min(r0 + 128, n);
    float mx = 0.f, sm = 0.f;
    int cur = -1;
    for (int r = r0 + sub; r < rend; r += 2) {
        int b = batch[r];
        if (b != cur) {
            if (cur >= 0) {
                atomicMax((unsigned int*)&gmax[cur * 128 + c], __float_as_uint(mx));
                atomicAdd(&gsum[cur * 128 + c], sm);
            }
            cur = b; mx = 0.f; sm = 0.f;
        }
        float v = b2f(h[(size_t)r * 128 + c]);
        mx = fmaxf(mx, v);
        sm += v;
    }
    if (cur >= 0) {
        atomicMax((unsigned int*)&gmax[cur * 128 + c], __float_as_uint(mx));
        atomicAdd(&gsum[cur * 128 + c], sm);
    }
}

__global__ __launch_bounds__(256) void k_final(const float* __restrict__ gmax, const float* __restrict__ gsum,
                                               const float* __restrict__ cntG, float* __restrict__ out,
                                               int G, int L)
{
    int i = blockIdx.x * 256 + threadIdx.x;
    int tot = L * G * 128;
    if (i >= tot) return;
    int c = i & 127;
    int g = (i >> 7) % G;
    int l = i / (G * 128);
    float ct = fmaxf(cntG[g], 1.0f);
    out[(size_t)g * (L * 256) + l * 256 + c]       = gmax[i];
    out[(size_t)g * (L * 256) + l * 256 + 128 + c] = gsum[i] / ct;
}

static inline int divup(int a, int b) { return (a + b - 1) / b; }

extern "C" void kernel_launch(void* const* d_in, const int* in_sizes, int n_in,
                              void* d_out, int out_size, void* d_ws, size_t ws_size,
                              hipStream_t stream)
{
    const float* x     = (const float*)d_in[0];
    const float* ew    = (const float*)d_in[1];
    const float* W1    = (const float*)d_in[2];
    const float* b1    = (const float*)d_in[3];
    const float* W2    = (const float*)d_in[4];
    const float* b2    = (const float*)d_in[5];
    const float* cW    = (const float*)d_in[6];
    const float* cB    = (const float*)d_in[7];
    const int*   ei    = (const int*)d_in[8];
    const int*   batch = (const int*)d_in[9];
    float* out = (float*)d_out;

    const int E = in_sizes[1];
    const int N = in_sizes[9];
    const int L = in_sizes[7] / 128;
    const int G = out_size / (L * 256);

    char* p = (char*)d_ws;
    auto carve = [&](size_t bytes) -> void* {
        void* q = (void*)p;
        p += (bytes + 255) & ~(size_t)255;
        return q;
    };
    u64*   pk       = (u64*)  carve((size_t)N * 8);
    float* dinv     = (float*)carve((size_t)N * 4);
    int*   start    = (int*)  carve((size_t)(N + 1) * 4);
    unsigned char* eslot = (unsigned char*)carve((size_t)E);
    int*   partials = (int*)  carve(4096);
    u32*   rec      = (u32*)  carve((size_t)E * 4);
    float* gmax     = (float*)carve((size_t)L * G * 128 * 4);
    float* gsum     = (float*)carve((size_t)L * G * 128 * 4);
    float* cntG     = (float*)carve((size_t)G * 4);
    unsigned short* wf[5];
    for (int i = 0; i < 5; ++i) wf[i] = (unsigned short*)carve(16384 * 2);
    unsigned short* xwb = (unsigned short*)carve((size_t)N * 128 * 2);
    unsigned short* hbA = (unsigned short*)carve((size_t)N * 128 * 2);
    unsigned short* hbB = (unsigned short*)carve((size_t)N * 128 * 2);

    const int npool = L * G * 128;

    // --- preprocessing -----------------------------------------------------
    {
        int mx = N > npool ? N : npool;
        k_init<<<divup(mx, 256), 256, 0, stream>>>(pk, gmax, gsum, N, npool);
    }
    k_phase1<<<divup(E, 256), 256, 0, stream>>>(ei, ew, pk, eslot, E);
    k_gcnt<<<1, 64, 0, stream>>>(batch, cntG, N, G);

    int nb1 = divup(N, 1024);
    k_scan1<<<nb1, 256, 0, stream>>>(pk, start, dinv, partials, N);
    k_scan2<<<1, 256, 0, stream>>>(partials, nb1);
    k_scan3<<<divup(N, 256), 256, 0, stream>>>(start, partials, N, E);
    k_phase2<<<divup(E, 256), 256, 0, stream>>>(ei, ew, dinv, start, eslot, rec, E);

    // --- weight fragment linearization ------------------------------------
    k_wfrag<<<8, 256, 0, stream>>>(W1, wf[0]);
    k_wfrag<<<8, 256, 0, stream>>>(W2, wf[1]);
    for (int l = 0; l < L && l < 3; ++l)
        k_wfrag<<<8, 256, 0, stream>>>(cW + (size_t)l * 16384, wf[2 + l]);

    // --- dense encoder -----------------------------------------------------
    int gblocks = divup(N, 64);
    k_gemm_mf<<<gblocks, 256, 0, stream>>>(nullptr, x, wf[0], b1, hbA, 1, N);
    k_gemm_mf<<<gblocks, 256, 0, stream>>>(hbA, nullptr, wf[1], b2, hbB, 1, N);

    // --- conv layers + pooling --------------------------------------------
    int ablocks = divup(N, 4);
    int pblocks = divup(N, 128);
    unsigned short* cur = hbB;
    unsigned short* alt = hbA;
    for (int l = 0; l < L; ++l) {
        k_gemm_mf<<<gblocks, 256, 0, stream>>>(cur, nullptr, wf[2 + (l < 3 ? l : 2)], nullptr, xwb, 0, N);
        k_agg<<<ablocks, 256, 0, stream>>>((const u32*)xwb, start, rec, dinv,
                                           cB + (size_t)l * 128, (u32*)alt, N);
        k_pool<<<pblocks, 256, 0, stream>>>(alt, batch, gmax + (size_t)l * G * 128,
                                            gsum + (size_t)l * G * 128, N);
        unsigned short* tmp = cur; cur = alt; alt = tmp;
    }

    k_final<<<divup(L * G * 128, 256), 256, 0, stream>>>(gmax, gsum, cntG, out, G, L);
}

// Round 9
// 481.142 us; speedup vs baseline: 1.1440x; 1.0898x over previous
//
#include <hip/hip_runtime.h>

// ---------------------------------------------------------------------------
// CustomGCN: 2 dense layers + 3 GCNConv layers + per-layer (max||mean) pool.
// R1: binary-search cntG.  R2: bf16 pipeline + MFMA GEMMs + bf16 gather.
// R3: 8-deep agg gather pipeline.  R4: one u64 atomic/edge CSC build.
// R5: interleaved CSC record.  R6: 4B rec ((bf16w)<<17|src), u8 eslot.
// R7: agg back to 8-deep (16-deep regressed).
// R8: block-range FUSION to overlap the atomic-bound CSC chain with the
//     MFMA-bound GEMM chain (phase1||gemm1, scan1||gemm2, scan2||conv0,
//     pool(l)||conv(l+1)). phase1 is 73us of idle VALU/MFMA — GEMMs ride free.
// ---------------------------------------------------------------------------

typedef __attribute__((ext_vector_type(8))) short bf16x8;
typedef __attribute__((ext_vector_type(4))) float f32x4;
typedef unsigned long long u64;
typedef unsigned int u32;

#define FRACBITS 52
#define FRACMASK ((1ULL << FRACBITS) - 1ULL)

__device__ __forceinline__ unsigned short f2b(float f) {  // RNE f32->bf16
    unsigned int u = __float_as_uint(f);
    return (unsigned short)((u + 0x7fffu + ((u >> 16) & 1u)) >> 16);
}
__device__ __forceinline__ float b2f(unsigned short h) {
    return __uint_as_float((unsigned int)h << 16);
}

// ---------------- device bodies --------------------------------------------

// MFMA GEMM strip: C[M,128] = A[M,128] @ W[128,128]; bidx indexes 4-wave blocks
__device__ __forceinline__ void gemm_dev(int bidx, int t,
                                         const unsigned short* __restrict__ A,
                                         const float* __restrict__ Af32,
                                         const unsigned short* __restrict__ Wf,
                                         const float* __restrict__ bias,
                                         unsigned short* __restrict__ C,
                                         int relu, int M)
{
    int lane = t & 63, w = t >> 6;
    int s = bidx * 4 + w;
    if (s * 16 >= M) return;
    int r0 = s * 16;
    int row = r0 + (lane & 15);
    int k0 = (lane >> 4) * 8;

    bf16x8 af[4];
    if (A) {
#pragma unroll
        for (int kt = 0; kt < 4; ++kt) {
            bf16x8 a = {0,0,0,0,0,0,0,0};
            if (row < M) a = *(const bf16x8*)&A[(size_t)row * 128 + k0 + kt * 32];
            af[kt] = a;
        }
    } else {
#pragma unroll
        for (int kt = 0; kt < 4; ++kt) {
            bf16x8 a = {0,0,0,0,0,0,0,0};
            if (row < M) {
                const float4* A4 = (const float4*)(Af32 + (size_t)row * 128 + k0 + kt * 32);
                float4 p = A4[0], q = A4[1];
                a[0] = (short)f2b(p.x); a[1] = (short)f2b(p.y);
                a[2] = (short)f2b(p.z); a[3] = (short)f2b(p.w);
                a[4] = (short)f2b(q.x); a[5] = (short)f2b(q.y);
                a[6] = (short)f2b(q.z); a[7] = (short)f2b(q.w);
            }
            af[kt] = a;
        }
    }

    int orow = r0 + 4 * (lane >> 4);
    int ocol = lane & 15;
#pragma unroll
    for (int ct = 0; ct < 8; ++ct) {
        f32x4 acc = {0.f, 0.f, 0.f, 0.f};
#pragma unroll
        for (int kt = 0; kt < 4; ++kt) {
            bf16x8 b = *(const bf16x8*)&Wf[(size_t)(((ct << 2) | kt) * 64 + lane) * 8];
            acc = __builtin_amdgcn_mfma_f32_16x16x32_bf16(af[kt], b, acc, 0, 0, 0);
        }
        float bv = bias ? bias[ct * 16 + ocol] : 0.f;
#pragma unroll
        for (int j = 0; j < 4; ++j) {
            int rr = orow + j;
            if (rr < M) {
                float v = acc[j] + bv;
                if (relu) v = fmaxf(v, 0.f);
                C[(size_t)rr * 128 + ct * 16 + ocol] = f2b(v);
            }
        }
    }
}

// run-based pooling over sorted batch; h >= 0 post-relu
__device__ __forceinline__ void pool_dev(int bidx, int t,
                                         const unsigned short* __restrict__ h,
                                         const int* __restrict__ batch,
                                         float* gmax, float* gsum, int n)
{
    int c = t & 127, sub = t >> 7;
    int r0 = bidx * 128;
    int rend = min(r0 + 128, n);
    float mx = 0.f, sm = 0.f;
    int cur = -1;
    for (int r = r0 + sub; r < rend; r += 2) {
        int b = batch[r];
        if (b != cur) {
            if (cur >= 0) {
                atomicMax((unsigned int*)&gmax[cur * 128 + c], __float_as_uint(mx));
                atomicAdd(&gsum[cur * 128 + c], sm);
            }
            cur = b; mx = 0.f; sm = 0.f;
        }
        float v = b2f(h[(size_t)r * 128 + c]);
        mx = fmaxf(mx, v);
        sm += v;
    }
    if (cur >= 0) {
        atomicMax((unsigned int*)&gmax[cur * 128 + c], __float_as_uint(mx));
        atomicAdd(&gsum[cur * 128 + c], sm);
    }
}

// ---------------- fused kernels --------------------------------------------

// init(pk,gmax,gsum) || wfrag x5 || gcnt
__global__ __launch_bounds__(256) void k_setup(u64* __restrict__ pk,
                                               float* __restrict__ gmax, float* __restrict__ gsum,
                                               int n, int npool,
                                               const float* __restrict__ W1, const float* __restrict__ W2,
                                               const float* __restrict__ cW,
                                               unsigned short* __restrict__ wfall,
                                               int nInit, int nWf,
                                               const int* __restrict__ batch, float* __restrict__ cntG, int g)
{
    int b = blockIdx.x;
    if (b < nInit) {
        int i = b * 256 + threadIdx.x;
        if (i < n) pk[i] = 0ULL;
        if (i < npool) { gmax[i] = 0.0f; gsum[i] = 0.0f; }
    } else if (b < nInit + nWf) {
        int wb = b - nInit;
        int m = wb >> 3;
        const float* W = (m == 0) ? W1 : (m == 1) ? W2 : (cW + (size_t)(m - 2) * 16384);
        unsigned short* Wf = wfall + (size_t)m * 16384;
        int idx = (wb & 7) * 256 + threadIdx.x;   // [0, 2048)
        int ctkt = idx >> 6, lane = idx & 63;
        int kt = ctkt & 3, ct = ctkt >> 2;
        int k0 = kt * 32 + (lane >> 4) * 8;
        int col = ct * 16 + (lane & 15);
        bf16x8 v;
#pragma unroll
        for (int j = 0; j < 8; ++j) v[j] = (short)f2b(W[(k0 + j) * 128 + col]);
        *(bf16x8*)&Wf[(size_t)idx * 8] = v;
    } else {
        int t = threadIdx.x;
        if (t < g) {
            int lo0 = 0, hi0 = n;
            while (lo0 < hi0) { int m = (lo0 + hi0) >> 1; if (batch[m] < t) lo0 = m + 1; else hi0 = m; }
            int lo1 = lo0, hi1 = n, t1 = t + 1;
            while (lo1 < hi1) { int m = (lo1 + hi1) >> 1; if (batch[m] < t1) lo1 = m + 1; else hi1 = m; }
            cntG[t] = (float)(lo1 - lo0);
        }
    }
}

// phase1 (atomic CSC count/degree/slot) || encoder GEMM1 (f32 x -> hbA)
__global__ __launch_bounds__(256) void k_p1_gemm(const int* __restrict__ ei, const float* __restrict__ ew,
                                                 u64* pk, unsigned char* __restrict__ eslot, int e, int p1b,
                                                 const float* __restrict__ Af32,
                                                 const unsigned short* __restrict__ Wf,
                                                 const float* __restrict__ bias,
                                                 unsigned short* __restrict__ C, int M)
{
    if (blockIdx.x < p1b) {
        int i = blockIdx.x * 256 + threadIdx.x;
        if (i >= e) return;
        int c = ei[e + i];
        float w = ew[i];
        u64 fixed = (u64)((double)w * 4294967296.0);
        u64 packed = (1ULL << FRACBITS) | fixed;
        u64 old = atomicAdd(&pk[c], packed);
        eslot[i] = (unsigned char)(old >> FRACBITS);
    } else {
        gemm_dev(blockIdx.x - p1b, threadIdx.x, nullptr, Af32, Wf, bias, C, 1, M);
    }
}

// scan1 (block prefix of counts + dinv) || encoder GEMM2 (hbA -> hbB)
__global__ __launch_bounds__(256) void k_scan1_gemm(const u64* __restrict__ pk,
                                                    int* __restrict__ start, float* __restrict__ dinv,
                                                    int* __restrict__ partials, int n, int s1b,
                                                    const unsigned short* __restrict__ A,
                                                    const unsigned short* __restrict__ Wf,
                                                    const float* __restrict__ bias,
                                                    unsigned short* __restrict__ C, int M)
{
    __shared__ int s[256];
    if (blockIdx.x < s1b) {
        int t = threadIdx.x;
        int base = blockIdx.x * 1024 + t * 4;
        int v[4];
#pragma unroll
        for (int j = 0; j < 4; ++j) {
            int idx = base + j;
            if (idx < n) {
                u64 q = pk[idx];
                v[j] = (int)(q >> FRACBITS);
                float deg = 1.0f + (float)((double)(q & FRACMASK) * (1.0 / 4294967296.0));
                dinv[idx] = 1.0f / sqrtf(deg);
            } else v[j] = 0;
        }
        int tsum = v[0] + v[1] + v[2] + v[3];
        s[t] = tsum; __syncthreads();
        for (int off = 1; off < 256; off <<= 1) {
            int xv = (t >= off) ? s[t - off] : 0;
            __syncthreads();
            s[t] += xv;
            __syncthreads();
        }
        if (t == 255) partials[blockIdx.x] = s[255];
        int run = s[t] - tsum;
#pragma unroll
        for (int j = 0; j < 4; ++j) { int idx = base + j; if (idx < n) start[idx] = run; run += v[j]; }
    } else {
        gemm_dev(blockIdx.x - s1b, threadIdx.x, A, nullptr, Wf, bias, C, 1, M);
    }
}

// scan2 (single-block scan of partials) || conv GEMM l0 (hbB -> xwb)
__global__ __launch_bounds__(256) void k_scan2_gemm(int* partials, int nb,
                                                    const unsigned short* __restrict__ A,
                                                    const unsigned short* __restrict__ Wf,
                                                    unsigned short* __restrict__ C, int M)
{
    __shared__ int s[256];
    if (blockIdx.x == 0) {
        int t = threadIdx.x;
        int offset = 0;
        for (int b0 = 0; b0 < nb; b0 += 256) {
            int v = (b0 + t < nb) ? partials[b0 + t] : 0;
            s[t] = v; __syncthreads();
            for (int off = 1; off < 256; off <<= 1) {
                int xv = (t >= off) ? s[t - off] : 0;
                __syncthreads();
                s[t] += xv;
                __syncthreads();
            }
            int excl = s[t] - v;
            int tot = s[255];
            if (b0 + t < nb) partials[b0 + t] = offset + excl;
            offset += tot;
            __syncthreads();
        }
    } else {
        gemm_dev(blockIdx.x - 1, threadIdx.x, A, nullptr, Wf, nullptr, C, 0, M);
    }
}

__global__ __launch_bounds__(256) void k_scan3(int* __restrict__ start,
                                               const int* __restrict__ partials, int n, int total)
{
    int i = blockIdx.x * 256 + threadIdx.x;
    if (i < n) start[i] += partials[i >> 10];
    if (i == 0) start[n] = total;
}

// atomic-free fill: one 4B record ((bf16w)<<17 | src) per edge
__global__ __launch_bounds__(256) void k_phase2(const int* __restrict__ ei, const float* __restrict__ ew,
                                                const float* __restrict__ dinv,
                                                const int* __restrict__ start,
                                                const unsigned char* __restrict__ eslot,
                                                u32* __restrict__ rec, int e)
{
    int i = blockIdx.x * 256 + threadIdx.x;
    if (i >= e) return;
    int r = ei[i], c = ei[e + i];
    int idx = start[c] + eslot[i];
    float w = dinv[r] * ew[i] * dinv[c];           // w >= 0
    u32 wb = f2b(w);
    rec[idx] = (wb << 17) | (u32)r;                 // requires N < 2^17
}

// pull aggregation: 8-deep gather pipeline
__global__ __launch_bounds__(256) void k_agg(const u32* __restrict__ xw,
                                             const int* __restrict__ start,
                                             const u32* __restrict__ rec,
                                             const float* __restrict__ dinv, const float* __restrict__ bias,
                                             u32* __restrict__ hout, int n)
{
    int wid  = (blockIdx.x * 256 + threadIdx.x) >> 6;
    int lane = threadIdx.x & 63;
    if (wid >= n) return;
    float di = dinv[wid];
    float sn = di * di;
    u32 v = xw[(size_t)wid * 64 + lane];
    float ax = __uint_as_float(v << 16) * sn;
    float ay = __uint_as_float(v & 0xffff0000u) * sn;
    int s0 = start[wid], s1 = start[wid + 1];

    int j = s0;
    for (; j + 8 <= s1; j += 8) {
        u32 rc[8];
#pragma unroll
        for (int q = 0; q < 8; ++q) rc[q] = rec[j + q];
        u32 u[8];
#pragma unroll
        for (int q = 0; q < 8; ++q) u[q] = xw[(size_t)(rc[q] & 0x1FFFFu) * 64 + lane];
#pragma unroll
        for (int q = 0; q < 8; ++q) {
            float w = __uint_as_float((rc[q] >> 17) << 16);
            ax = fmaf(w, __uint_as_float(u[q] << 16), ax);
            ay = fmaf(w, __uint_as_float(u[q] & 0xffff0000u), ay);
        }
    }
    int rem = s1 - j;
    if (rem) {
        u32 rc[8];
#pragma unroll
        for (int q = 0; q < 8; ++q) rc[q] = (q < rem) ? rec[j + q] : 0u;
        u32 u[8];
#pragma unroll
        for (int q = 0; q < 8; ++q) u[q] = (q < rem) ? xw[(size_t)(rc[q] & 0x1FFFFu) * 64 + lane] : 0u;
#pragma unroll
        for (int q = 0; q < 8; ++q) {
            float w = __uint_as_float((rc[q] >> 17) << 16);
            ax = fmaf(w, __uint_as_float(u[q] << 16), ax);
            ay = fmaf(w, __uint_as_float(u[q] & 0xffff0000u), ay);
        }
    }

    ax = fmaxf(ax + bias[lane * 2], 0.f);
    ay = fmaxf(ay + bias[lane * 2 + 1], 0.f);
    hout[(size_t)wid * 64 + lane] = (u32)f2b(ax) | ((u32)f2b(ay) << 16);
}

// pool(l) || conv GEMM(l+1) — both read the same agg output h
__global__ __launch_bounds__(256) void k_pool_gemm(const unsigned short* __restrict__ h,
                                                   const int* __restrict__ batch,
                                                   float* gmax, float* gsum, int n, int pb,
                                                   const unsigned short* __restrict__ Wf,
                                                   unsigned short* __restrict__ C, int M)
{
    if (blockIdx.x < pb) {
        pool_dev(blockIdx.x, threadIdx.x, h, batch, gmax, gsum, n);
    } else {
        gemm_dev(blockIdx.x - pb, threadIdx.x, h, nullptr, Wf, nullptr, C, 0, M);
    }
}

__global__ __launch_bounds__(256) void k_pool(const unsigned short* __restrict__ h,
                                              const int* __restrict__ batch,
                                              float* gmax, float* gsum, int n)
{
    pool_dev(blockIdx.x, threadIdx.x, h, batch, gmax, gsum, n);
}

__global__ __launch_bounds__(256) void k_final(const float* __restrict__ gmax, const float* __restrict__ gsum,
                                               const float* __restrict__ cntG, float* __restrict__ out,
                                               int G, int L)
{
    int i = blockIdx.x * 256 + threadIdx.x;
    int tot = L * G * 128;
    if (i >= tot) return;
    int c = i & 127;
    int g = (i >> 7) % G;
    int l = i / (G * 128);
    float ct = fmaxf(cntG[g], 1.0f);
    out[(size_t)g * (L * 256) + l * 256 + c]       = gmax[i];
    out[(size_t)g * (L * 256) + l * 256 + 128 + c] = gsum[i] / ct;
}

static inline int divup(int a, int b) { return (a + b - 1) / b; }

extern "C" void kernel_launch(void* const* d_in, const int* in_sizes, int n_in,
                              void* d_out, int out_size, void* d_ws, size_t ws_size,
                              hipStream_t stream)
{
    const float* x     = (const float*)d_in[0];
    const float* ew    = (const float*)d_in[1];
    const float* W1    = (const float*)d_in[2];
    const float* b1    = (const float*)d_in[3];
    const float* W2    = (const float*)d_in[4];
    const float* b2    = (const float*)d_in[5];
    const float* cW    = (const float*)d_in[6];
    const float* cB    = (const float*)d_in[7];
    const int*   ei    = (const int*)d_in[8];
    const int*   batch = (const int*)d_in[9];
    float* out = (float*)d_out;

    const int E = in_sizes[1];
    const int N = in_sizes[9];
    const int L = in_sizes[7] / 128;
    const int G = out_size / (L * 256);

    char* p = (char*)d_ws;
    auto carve = [&](size_t bytes) -> void* {
        void* q = (void*)p;
        p += (bytes + 255) & ~(size_t)255;
        return q;
    };
    u64*   pk       = (u64*)  carve((size_t)N * 8);
    float* dinv     = (float*)carve((size_t)N * 4);
    int*   start    = (int*)  carve((size_t)(N + 1) * 4);
    unsigned char* eslot = (unsigned char*)carve((size_t)E);
    int*   partials = (int*)  carve(4096);
    u32*   rec      = (u32*)  carve((size_t)E * 4);
    float* gmax     = (float*)carve((size_t)L * G * 128 * 4);
    float* gsum     = (float*)carve((size_t)L * G * 128 * 4);
    float* cntG     = (float*)carve((size_t)G * 4);
    unsigned short* wfall = (unsigned short*)carve((size_t)(2 + 3) * 16384 * 2);
    unsigned short* xwb = (unsigned short*)carve((size_t)N * 128 * 2);
    unsigned short* hbA = (unsigned short*)carve((size_t)N * 128 * 2);
    unsigned short* hbB = (unsigned short*)carve((size_t)N * 128 * 2);

    const int npool = L * G * 128;
    const int nconv = (L < 3 ? L : 3);

    // --- setup: init || wfrag x(2+nconv) || gcnt ---------------------------
    int nInit = divup(N > npool ? N : npool, 256);
    int nWf = (2 + nconv) * 8;
    k_setup<<<nInit + nWf + 1, 256, 0, stream>>>(pk, gmax, gsum, N, npool,
                                                 W1, W2, cW, wfall, nInit, nWf,
                                                 batch, cntG, G);

    int p1b = divup(E, 256);
    int gblocks = divup(N, 64);
    int pblocks = divup(N, 128);
    int ablocks = divup(N, 4);

    // --- phase1 || GEMM1 ---------------------------------------------------
    k_p1_gemm<<<p1b + gblocks, 256, 0, stream>>>(ei, ew, pk, eslot, E, p1b,
                                                 x, wfall, b1, hbA, N);

    // --- scan1 || GEMM2 ----------------------------------------------------
    int nb1 = divup(N, 1024);
    k_scan1_gemm<<<nb1 + gblocks, 256, 0, stream>>>(pk, start, dinv, partials, N, nb1,
                                                    hbA, wfall + 16384, b2, hbB, N);

    // --- scan2 || conv GEMM l0 --------------------------------------------
    k_scan2_gemm<<<1 + gblocks, 256, 0, stream>>>(partials, nb1,
                                                  hbB, wfall + 2 * 16384, xwb, N);

    k_scan3<<<divup(N, 256), 256, 0, stream>>>(start, partials, N, E);
    k_phase2<<<divup(E, 256), 256, 0, stream>>>(ei, ew, dinv, start, eslot, rec, E);

    // --- conv layers: agg -> (pool || next conv GEMM) ----------------------
    unsigned short* cur = hbB;
    unsigned short* alt = hbA;
    for (int l = 0; l < L; ++l) {
        k_agg<<<ablocks, 256, 0, stream>>>((const u32*)xwb, start, rec, dinv,
                                           cB + (size_t)l * 128, (u32*)alt, N);
        if (l + 1 < L) {
            int wi = 2 + (l + 1 < nconv ? l + 1 : nconv - 1);
            k_pool_gemm<<<pblocks + gblocks, 256, 0, stream>>>(alt, batch,
                                                               gmax + (size_t)l * G * 128,
                                                               gsum + (size_t)l * G * 128, N, pblocks,
                                                               wfall + (size_t)wi * 16384, xwb, N);
        } else {
            k_pool<<<pblocks, 256, 0, stream>>>(alt, batch,
                                                gmax + (size_t)l * G * 128,
                                                gsum + (size_t)l * G * 128, N);
        }
        unsigned short* tmp = cur; cur = alt; alt = tmp;
    }

    k_final<<<divup(L * G * 128, 256), 256, 0, stream>>>(gmax, gsum, cntG, out, G, L);
}